// Round 1
// 123.058 us; speedup vs baseline: 1.0320x; 1.0320x over previous
//
#include <hip/hip_runtime.h>

#define NQ 22
#define DIM (1 << NQ)
#define TILE 2048
#define LOG_TILE 11

typedef float f32x4_t __attribute__((ext_vector_type(4)));

// Precompute B[l] = sum over pairs p>q (LSB positions 0..10) both set in l of
// U[(21-p)*22 + (21-q)].  2048 entries, written to workspace.
__global__ __launch_bounds__(256) void ryd_precompute_B(const float* __restrict__ U,
                                                        float* __restrict__ Btab) {
    int t = blockIdx.x * blockDim.x + threadIdx.x;  // 0..2047
    __shared__ float Us[NQ * NQ];
    for (int i = threadIdx.x; i < NQ * NQ; i += blockDim.x) Us[i] = U[i];
    __syncthreads();
    float b = 0.f;
    #pragma unroll
    for (int p = 1; p <= 10; ++p) {
        if ((t >> p) & 1) {
            #pragma unroll
            for (int q = 0; q < p; ++q) {
                if ((t >> q) & 1) b += Us[(21 - p) * NQ + (21 - q)];
            }
        }
    }
    Btab[t] = b;
}

#define ACC8(a0, a1, b0, b1)                                              \
    do {                                                                  \
        ar[0] += (a0).x; ar[1] += (a0).y; ar[2] += (a0).z; ar[3] += (a0).w; \
        ar[4] += (a1).x; ar[5] += (a1).y; ar[6] += (a1).z; ar[7] += (a1).w; \
        ai[0] += (b0).x; ai[1] += (b0).y; ai[2] += (b0).z; ai[3] += (b0).w; \
        ai[4] += (b1).x; ai[5] += (b1).y; ai[6] += (b1).z; ai[7] += (b1).w; \
    } while (0)

// LDS chunk swizzle (16B granularity): spreads one wave's ds_read_b128 lanes
// across all 8 bank groups.  c = 2*t + s  ->  c ^ ((c>>3)&1) flips s by t[2].
__device__ __forceinline__ int swz(int c) { return c ^ ((c >> 3) & 1); }

__global__ __launch_bounds__(256, 4) void ryd_main(
    const float* __restrict__ sr_g, const float* __restrict__ si_g,
    const float* __restrict__ rabi, const float* __restrict__ detune,
    const float* __restrict__ U, const float* __restrict__ Btab,
    float* __restrict__ out) {
    __shared__ float4 srv[TILE / 4];   // swizzled 16B chunks, 8 KB
    __shared__ float4 siv[TILE / 4];   // 8 KB
    __shared__ float AD[12];  // AD[0..10] = Dq[q] (cross column sums), AD[11] = A(h)

    const int h = blockIdx.x;        // high 11 bits of the basis index
    const int tid = threadIdx.x;     // 0..255
    const int m0 = tid << 3;         // local element base (this thread owns 8)
    const int base = h << LOG_TILE;  // global tile base

    // ---- (1) Own tile: first in the vm FIFO, so LDS staging waits only on these.
    float4 r0 = *(const float4*)(sr_g + base + m0);
    float4 r1 = *(const float4*)(sr_g + base + m0 + 4);
    float4 i0 = *(const float4*)(si_g + base + m0);
    float4 i1 = *(const float4*)(si_g + base + m0 + 4);

    // ---- (2) Cross-XCD partner tiles (h-bits 0..2 -> global bits 11..13).
    // Longest-latency path: issue now, hold in registers across the LDS phase.
    float4 fr[3][2], fi[3][2];
    #pragma unroll
    for (int j = 0; j < 3; ++j) {
        const float* pa = sr_g + ((h ^ (1 << j)) << LOG_TILE) + m0;
        const float* pb = si_g + ((h ^ (1 << j)) << LOG_TILE) + m0;
        fr[j][0] = *(const float4*)pa;
        fr[j][1] = *(const float4*)(pa + 4);
        fi[j][0] = *(const float4*)pb;
        fi[j][1] = *(const float4*)(pb + 4);
    }

    // ---- (3) Btab (consumed in the epilogue; anywhere in the FIFO is fine).
    float4 B0 = *(const float4*)(Btab + m0);
    float4 B1 = *(const float4*)(Btab + m0 + 4);

    // ---- Stage own tile to LDS (swizzled chunks).
    srv[swz(2 * tid)]     = r0;
    srv[swz(2 * tid + 1)] = r1;
    siv[swz(2 * tid)]     = i0;
    siv[swz(2 * tid + 1)] = i1;

    // Threads 0..10: Dq[q] = sum_{hp set in h} U[(10-hp)*22 + (21-q)]
    // Thread 11:     A(h)  = sum over pairs hp>hq set in h of U[(10-hp)*22 + (10-hq)]
    if (tid < 11) {
        int q = tid;
        float d = 0.f;
        #pragma unroll
        for (int hp = 0; hp <= 10; ++hp)
            if ((h >> hp) & 1) d += U[(10 - hp) * NQ + (21 - q)];
        AD[q] = d;
    } else if (tid == 11) {
        float a = 0.f;
        #pragma unroll
        for (int hp = 1; hp <= 10; ++hp) {
            if ((h >> hp) & 1) {
                #pragma unroll
                for (int hq = 0; hq < hp; ++hq)
                    if ((h >> hq) & 1) a += U[(10 - hp) * NQ + (10 - hq)];
            }
        }
        AD[11] = a;
    }

    float pr[8]  = {r0.x, r0.y, r0.z, r0.w, r1.x, r1.y, r1.z, r1.w};
    float pi_[8] = {i0.x, i0.y, i0.z, i0.w, i1.x, i1.y, i1.z, i1.w};

    __syncthreads();

    // ---- Flip bits 0..2: partners live in this thread's own registers.
    float ar[8], ai[8];
    #pragma unroll
    for (int e = 0; e < 8; ++e) {
        ar[e] = pr[e ^ 1] + pr[e ^ 2] + pr[e ^ 4];
        ai[e] = pi_[e ^ 1] + pi_[e ^ 2] + pi_[e ^ 4];
    }

    // ---- Flip bits 3..10: partner 8-blocks inside the LDS tile (swizzled b128).
    #pragma unroll
    for (int jj = 0; jj < 8; ++jj) {
        int p = tid ^ (1 << jj);
        float4 a0 = srv[swz(2 * p)];
        float4 a1 = srv[swz(2 * p + 1)];
        float4 b0 = siv[swz(2 * p)];
        float4 b1 = siv[swz(2 * p + 1)];
        ACC8(a0, a1, b0, b1);
    }

    // ---- Consume the cross-XCD prefetch (latency hidden by the LDS phase).
    #pragma unroll
    for (int j = 0; j < 3; ++j) ACC8(fr[j][0], fr[j][1], fi[j][0], fi[j][1]);

    // ---- Flip bits 14..21 (h-bits 3..10): same-XCD L2 hits; process in pairs
    // so 8 float4 loads are in flight per batch.
    #pragma unroll
    for (int jj = 3; jj < 11; jj += 2) {
        const float* pa = sr_g + ((h ^ (1 << jj)) << LOG_TILE) + m0;
        const float* pb = si_g + ((h ^ (1 << jj)) << LOG_TILE) + m0;
        const float* pc = sr_g + ((h ^ (2 << jj)) << LOG_TILE) + m0;
        const float* pd = si_g + ((h ^ (2 << jj)) << LOG_TILE) + m0;
        float4 a0 = *(const float4*)pa;
        float4 a1 = *(const float4*)(pa + 4);
        float4 b0 = *(const float4*)pb;
        float4 b1 = *(const float4*)(pb + 4);
        float4 c0 = *(const float4*)pc;
        float4 c1 = *(const float4*)(pc + 4);
        float4 d0 = *(const float4*)pd;
        float4 d1 = *(const float4*)(pd + 4);
        ACC8(a0, a1, b0, b1);
        ACC8(c0, c1, d0, d1);
    }

    // ---- Diagonal: diag(b) = A + B[l] + sum_{q set in l} Dq[q] - det*popc(b)
    const float det = detune[0];
    const float hrabi = 0.5f * rabi[0];
    float Dq0 = AD[0] - det;
    float Dq1 = AD[1] - det;
    float Dq2 = AD[2] - det;
    float diagBase = AD[11] - det * (float)__popc((unsigned)h);
    #pragma unroll
    for (int j = 0; j < 8; ++j)
        if ((tid >> j) & 1) diagBase += AD[j + 3] - det;

    float Bv[8] = {B0.x, B0.y, B0.z, B0.w, B1.x, B1.y, B1.z, B1.w};

    float orv[8], oiv[8];
    #pragma unroll
    for (int e = 0; e < 8; ++e) {
        float d = diagBase + Bv[e];
        if (e & 1) d += Dq0;
        if (e & 2) d += Dq1;
        if (e & 4) d += Dq2;
        orv[e] = hrabi * ar[e] + d * pr[e];
        oiv[e] = hrabi * ai[e] + d * pi_[e];
    }

    // ---- Non-temporal stores: don't let the 4 MB/XCD of output write-allocate
    // evict the 4 MB/XCD partner-read working set from L2.
    f32x4_t o0 = {orv[0], orv[1], orv[2], orv[3]};
    f32x4_t o1 = {orv[4], orv[5], orv[6], orv[7]};
    f32x4_t o2 = {oiv[0], oiv[1], oiv[2], oiv[3]};
    f32x4_t o3 = {oiv[4], oiv[5], oiv[6], oiv[7]};
    __builtin_nontemporal_store(o0, (f32x4_t*)(out + base + m0));
    __builtin_nontemporal_store(o1, (f32x4_t*)(out + base + m0 + 4));
    __builtin_nontemporal_store(o2, (f32x4_t*)(out + DIM + base + m0));
    __builtin_nontemporal_store(o3, (f32x4_t*)(out + DIM + base + m0 + 4));
}

extern "C" void kernel_launch(void* const* d_in, const int* in_sizes, int n_in,
                              void* d_out, int out_size, void* d_ws, size_t ws_size,
                              hipStream_t stream) {
    const float* state_real = (const float*)d_in[0];
    const float* state_imag = (const float*)d_in[1];
    const float* rabi       = (const float*)d_in[2];
    const float* detune     = (const float*)d_in[3];
    const float* U          = (const float*)d_in[4];
    float* Btab = (float*)d_ws;  // 2048 floats = 8 KB
    float* out  = (float*)d_out;

    ryd_precompute_B<<<TILE / 256, 256, 0, stream>>>(U, Btab);
    ryd_main<<<DIM / TILE, 256, 0, stream>>>(state_real, state_imag, rabi, detune,
                                             U, Btab, out);
}

// Round 2
// 118.817 us; speedup vs baseline: 1.0688x; 1.0357x over previous
//
#include <hip/hip_runtime.h>

#define NQ 22
#define DIM (1 << NQ)
#define TILE 2048
#define LOG_TILE 11

typedef float f32x4_t __attribute__((ext_vector_type(4)));

// Precompute B[l] = sum over pairs p>q (LSB positions 0..10) both set in l of
// U[(21-p)*22 + (21-q)].  2048 entries, written to workspace.
__global__ __launch_bounds__(256) void ryd_precompute_B(const float* __restrict__ U,
                                                        float* __restrict__ Btab) {
    int t = blockIdx.x * blockDim.x + threadIdx.x;  // 0..2047
    __shared__ float Us[NQ * NQ];
    for (int i = threadIdx.x; i < NQ * NQ; i += blockDim.x) Us[i] = U[i];
    __syncthreads();
    float b = 0.f;
    #pragma unroll
    for (int p = 1; p <= 10; ++p) {
        if ((t >> p) & 1) {
            #pragma unroll
            for (int q = 0; q < p; ++q) {
                if ((t >> q) & 1) b += Us[(21 - p) * NQ + (21 - q)];
            }
        }
    }
    Btab[t] = b;
}

#define ACC8(a0, a1, b0, b1)                                              \
    do {                                                                  \
        ar[0] += (a0).x; ar[1] += (a0).y; ar[2] += (a0).z; ar[3] += (a0).w; \
        ar[4] += (a1).x; ar[5] += (a1).y; ar[6] += (a1).z; ar[7] += (a1).w; \
        ai[0] += (b0).x; ai[1] += (b0).y; ai[2] += (b0).z; ai[3] += (b0).w; \
        ai[4] += (b1).x; ai[5] += (b1).y; ai[6] += (b1).z; ai[7] += (b1).w; \
    } while (0)

// Issue the 4 float4 loads of one partner tile into NAMED registers (no arrays,
// so everything stays in VGPRs with static indices).
#define LOAD_FLIP(v, bit)                                                 \
    float4 v##r0, v##r1, v##i0, v##i1;                                    \
    {                                                                     \
        const int pb_ = ((h ^ (bit)) << LOG_TILE) + m0;                   \
        v##r0 = *(const float4*)(sr_g + pb_);                             \
        v##r1 = *(const float4*)(sr_g + pb_ + 4);                         \
        v##i0 = *(const float4*)(si_g + pb_);                             \
        v##i1 = *(const float4*)(si_g + pb_ + 4);                         \
    }
#define CONSUME(v) ACC8(v##r0, v##r1, v##i0, v##i1)

// LDS chunk swizzle (16B granularity): spreads one wave's ds_read_b128 lanes
// across all 8 bank groups.  c = 2*t + s  ->  c ^ ((c>>3)&1) flips s by t[2].
__device__ __forceinline__ int swz(int c) { return c ^ ((c >> 3) & 1); }

// min-waves/EU = 2: lowers the scheduler's occupancy target so it keeps the
// software-pipelined loads in flight instead of crushing to 64 VGPR / depth-1.
__global__ __launch_bounds__(256, 2) void ryd_main(
    const float* __restrict__ sr_g, const float* __restrict__ si_g,
    const float* __restrict__ rabi, const float* __restrict__ detune,
    const float* __restrict__ U, const float* __restrict__ Btab,
    float* __restrict__ out) {
    __shared__ float4 srv[TILE / 4];   // swizzled 16B chunks, 8 KB
    __shared__ float4 siv[TILE / 4];   // 8 KB
    __shared__ float AD[12];  // AD[0..10] = Dq[q] (cross column sums), AD[11] = A(h)

    const int h = blockIdx.x;        // high 11 bits of the basis index
    const int tid = threadIdx.x;     // 0..255
    const int m0 = tid << 3;         // local element base (this thread owns 8)
    const int base = h << LOG_TILE;  // global tile base

    // ---- (1) Own tile: first in the vm FIFO, so LDS staging waits only on these.
    float4 r0 = *(const float4*)(sr_g + base + m0);
    float4 r1 = *(const float4*)(sr_g + base + m0 + 4);
    float4 i0 = *(const float4*)(si_g + base + m0);
    float4 i1 = *(const float4*)(si_g + base + m0 + 4);

    // ---- (2) Cross-XCD partner tiles (h-bits 0..2 -> global bits 11..13).
    // Longest latency path: in flight across the whole LDS phase.
    LOAD_FLIP(f0, 1)
    LOAD_FLIP(f1, 2)
    LOAD_FLIP(f2, 4)

    // ---- (3) Batch A of same-XCD flips: also in flight across the LDS phase.
    LOAD_FLIP(g3, 8)
    LOAD_FLIP(g4, 16)
    LOAD_FLIP(g5, 32)

    // ---- Stage own tile to LDS (swizzled chunks); waits only on the 4 own loads.
    srv[swz(2 * tid)]     = r0;
    srv[swz(2 * tid + 1)] = r1;
    siv[swz(2 * tid)]     = i0;
    siv[swz(2 * tid + 1)] = i1;

    // Threads 0..10: Dq[q] = sum_{hp set in h} U[(10-hp)*22 + (21-q)]
    // Thread 11:     A(h)  = sum over pairs hp>hq set in h of U[(10-hp)*22 + (10-hq)]
    if (tid < 11) {
        int q = tid;
        float d = 0.f;
        #pragma unroll
        for (int hp = 0; hp <= 10; ++hp)
            if ((h >> hp) & 1) d += U[(10 - hp) * NQ + (21 - q)];
        AD[q] = d;
    } else if (tid == 11) {
        float a = 0.f;
        #pragma unroll
        for (int hp = 1; hp <= 10; ++hp) {
            if ((h >> hp) & 1) {
                #pragma unroll
                for (int hq = 0; hq < hp; ++hq)
                    if ((h >> hq) & 1) a += U[(10 - hp) * NQ + (10 - hq)];
            }
        }
        AD[11] = a;
    }

    float pr[8]  = {r0.x, r0.y, r0.z, r0.w, r1.x, r1.y, r1.z, r1.w};
    float pi_[8] = {i0.x, i0.y, i0.z, i0.w, i1.x, i1.y, i1.z, i1.w};

    __syncthreads();

    // ---- Flip bits 0..2: partners live in this thread's own registers.
    float ar[8], ai[8];
    #pragma unroll
    for (int e = 0; e < 8; ++e) {
        ar[e] = pr[e ^ 1] + pr[e ^ 2] + pr[e ^ 4];
        ai[e] = pi_[e ^ 1] + pi_[e ^ 2] + pi_[e ^ 4];
    }

    // ---- Flip bits 3..10: partner 8-blocks inside the LDS tile (swizzled b128).
    #pragma unroll
    for (int jj = 0; jj < 8; ++jj) {
        int p = tid ^ (1 << jj);
        float4 a0 = srv[swz(2 * p)];
        float4 a1 = srv[swz(2 * p + 1)];
        float4 b0 = siv[swz(2 * p)];
        float4 b1 = siv[swz(2 * p + 1)];
        ACC8(a0, a1, b0, b1);
    }

    // ---- Batch B issued before any global consumption: FIFO stays >= 12 deep.
    LOAD_FLIP(g6, 64)
    LOAD_FLIP(g7, 128)
    LOAD_FLIP(g8, 256)

    // ---- Consume cross-XCD prefetch (latency long hidden; 24 loads still out).
    CONSUME(f0);
    CONSUME(f1);
    CONSUME(f2);

    // ---- Batch C + Btab issued before consuming batch A.
    LOAD_FLIP(g9, 512)
    LOAD_FLIP(g10, 1024)
    float4 B0 = *(const float4*)(Btab + m0);
    float4 B1 = *(const float4*)(Btab + m0 + 4);

    // ---- Consume A (22 loads outstanding), then B (10 out), then C (2 out).
    CONSUME(g3);
    CONSUME(g4);
    CONSUME(g5);
    CONSUME(g6);
    CONSUME(g7);
    CONSUME(g8);
    CONSUME(g9);
    CONSUME(g10);

    // ---- Diagonal: diag(b) = A + B[l] + sum_{q set in l} Dq[q] - det*popc(b)
    const float det = detune[0];
    const float hrabi = 0.5f * rabi[0];
    float Dq0 = AD[0] - det;
    float Dq1 = AD[1] - det;
    float Dq2 = AD[2] - det;
    float diagBase = AD[11] - det * (float)__popc((unsigned)h);
    #pragma unroll
    for (int j = 0; j < 8; ++j)
        if ((tid >> j) & 1) diagBase += AD[j + 3] - det;

    float Bv[8] = {B0.x, B0.y, B0.z, B0.w, B1.x, B1.y, B1.z, B1.w};

    float orv[8], oiv[8];
    #pragma unroll
    for (int e = 0; e < 8; ++e) {
        float d = diagBase + Bv[e];
        if (e & 1) d += Dq0;
        if (e & 2) d += Dq1;
        if (e & 4) d += Dq2;
        orv[e] = hrabi * ar[e] + d * pr[e];
        oiv[e] = hrabi * ai[e] + d * pi_[e];
    }

    // ---- Non-temporal stores: don't let the 4 MB/XCD of output write-allocate
    // evict the 4 MB/XCD partner-read working set from L2.
    f32x4_t o0 = {orv[0], orv[1], orv[2], orv[3]};
    f32x4_t o1 = {orv[4], orv[5], orv[6], orv[7]};
    f32x4_t o2 = {oiv[0], oiv[1], oiv[2], oiv[3]};
    f32x4_t o3 = {oiv[4], oiv[5], oiv[6], oiv[7]};
    __builtin_nontemporal_store(o0, (f32x4_t*)(out + base + m0));
    __builtin_nontemporal_store(o1, (f32x4_t*)(out + base + m0 + 4));
    __builtin_nontemporal_store(o2, (f32x4_t*)(out + DIM + base + m0));
    __builtin_nontemporal_store(o3, (f32x4_t*)(out + DIM + base + m0 + 4));
}

extern "C" void kernel_launch(void* const* d_in, const int* in_sizes, int n_in,
                              void* d_out, int out_size, void* d_ws, size_t ws_size,
                              hipStream_t stream) {
    const float* state_real = (const float*)d_in[0];
    const float* state_imag = (const float*)d_in[1];
    const float* rabi       = (const float*)d_in[2];
    const float* detune     = (const float*)d_in[3];
    const float* U          = (const float*)d_in[4];
    float* Btab = (float*)d_ws;  // 2048 floats = 8 KB
    float* out  = (float*)d_out;

    ryd_precompute_B<<<TILE / 256, 256, 0, stream>>>(U, Btab);
    ryd_main<<<DIM / TILE, 256, 0, stream>>>(state_real, state_imag, rabi, detune,
                                             U, Btab, out);
}